// Round 1
// baseline (4027.679 us; speedup 1.0000x reference)
//
#include <hip/hip_runtime.h>

using u16 = unsigned short;
using u32 = unsigned int;
typedef __attribute__((ext_vector_type(8))) short bf16x8;
typedef __attribute__((ext_vector_type(4))) float f32x4;

__device__ __forceinline__ u16 f2b(float f) {
  u32 u = __float_as_uint(f);
  return (u16)((u + 0x7fffu + ((u >> 16) & 1u)) >> 16);   // RNE
}
__device__ __forceinline__ float b2fs(short v) { return __uint_as_float(((u32)(u16)v) << 16); }

// ---------------- workspace layout (all offsets 256B-aligned) ----------------
static constexpr size_t HEX_SZ    = (size_t)513 * 512 * 4;           // tagged h-exchange, (T+1)x512 u32
static constexpr size_t OFF_HEXF0 = 0;
static constexpr size_t OFF_HEXB0 = OFF_HEXF0 + HEX_SZ;
static constexpr size_t OFF_HEXF1 = OFF_HEXB0 + HEX_SZ;
static constexpr size_t OFF_HEXB1 = OFF_HEXF1 + HEX_SZ;
static constexpr size_t OFF_LACC  = OFF_HEXB1 + HEX_SZ;              // 256 floats
static constexpr size_t ZERO_BYTES= OFF_LACC + 1024;                 // memset range
static constexpr size_t OFF_XB    = ZERO_BYTES;                      // 512x256 bf16 (embed, padded K)
static constexpr size_t OFF_WIH0F = OFF_XB    + (size_t)512*256*2;
static constexpr size_t OFF_WIH0B = OFF_WIH0F + (size_t)2048*256*2;
static constexpr size_t OFF_WIH1F = OFF_WIH0B + (size_t)2048*256*2;
static constexpr size_t OFF_WIH1B = OFF_WIH1F + (size_t)2048*1024*2;
static constexpr size_t OFF_BSALL = OFF_WIH1B + (size_t)2048*1024*2; // 8192x512 bf16 (Ws1 reordered)
static constexpr size_t OFF_BLALL = OFF_BSALL + (size_t)8192*512*2;  // 6144x512 bf16 (Wl1 reordered)
static constexpr size_t OFF_HCAT0 = OFF_BLALL + (size_t)6144*512*2;  // 512x1024 bf16
static constexpr size_t OFF_HCAT1 = OFF_HCAT0 + (size_t)512*1024*2;
static constexpr size_t OFF_XG0F  = OFF_HCAT1 + (size_t)512*1024*2;  // 512x2048 f32
static constexpr size_t OFF_XG0B  = OFF_XG0F  + (size_t)512*2048*4;
static constexpr size_t OFF_XG1F  = OFF_XG0B  + (size_t)512*2048*4;
static constexpr size_t OFF_XG1B  = OFF_XG1F  + (size_t)512*2048*4;
static constexpr size_t OFF_PFS   = OFF_XG1B  + (size_t)512*2048*4;  // 512x4096 f32
static constexpr size_t OFF_PBS   = OFF_PFS   + (size_t)512*4096*4;
static constexpr size_t OFF_PFL   = OFF_PBS   + (size_t)512*4096*4;  // 512x3072 f32
static constexpr size_t OFF_PBL   = OFF_PFL   + (size_t)512*3072*4;

// ---------------- embedding: x[t] = [W_word[w], W_tag[tg], 0-pad] as bf16 (K padded 250->256) ----
__global__ __launch_bounds__(64) void k_embed(const int* __restrict__ wi, const int* __restrict__ ti,
                                              const float* __restrict__ Ww, const float* __restrict__ Wt,
                                              u16* __restrict__ x) {
  int t = blockIdx.x;
  int w = wi[t], tg = ti[t];
  for (int c = threadIdx.x; c < 256; c += 64) {
    float v = 0.f;
    if (c < 200) v = Ww[(size_t)w * 200 + c];
    else if (c < 250) v = Wt[(size_t)tg * 50 + (c - 200)];
    x[(size_t)t * 256 + c] = f2b(v);
  }
}

// ---------------- fp32 -> bf16 cast with K padding ----------------
__global__ __launch_bounds__(256) void k_castpad(const float* __restrict__ src, u16* __restrict__ dst,
                                                 int K, int Kp, int total) {
  int i = blockIdx.x * 256 + threadIdx.x;
  if (i >= total) return;
  int n = i / Kp, k = i - n * Kp;
  dst[i] = (k < K) ? f2b(src[(size_t)n * K + k]) : (u16)0;
}

// ---- reorder W1 (HID x NC) -> B (NB*1024 x 512) with row n=k*1024+h: B[n][u]=W1[h][k*512+u] ----
__global__ __launch_bounds__(256) void k_reorder(const float* __restrict__ src, u16* __restrict__ dst,
                                                 int NC, int total) {
  int i = blockIdx.x * 256 + threadIdx.x;
  if (i >= total) return;
  int u = i & 511;
  int nidx = i >> 9;
  int k = nidx >> 10, h = nidx & 1023;
  dst[i] = f2b(src[(size_t)h * NC + k * 512 + u]);
}

// ---------------- bf16 MFMA GEMM: C(MxN) = A(MxK) @ B(NxK)^T (+bias) ----------------
// 128x128 tile, BK=32, 256 threads = 4 waves (2x2), wave does 64x64 via 4x4 16x16x32 frags.
#define AST 40  // LDS row stride in ushorts (80B = 5*16B, conflict-free b128 reads)
__global__ __launch_bounds__(256) void k_gemm(const u16* __restrict__ A, int lda,
                                              const u16* __restrict__ B, int ldb,
                                              float* __restrict__ C, int ldc,
                                              const float* __restrict__ bias, int K) {
  __shared__ u16 As[128 * AST];
  __shared__ u16 Bs[128 * AST];
  int tid = threadIdx.x;
  int lane = tid & 63, wave = tid >> 6;
  int wm = wave >> 1, wn = wave & 1;
  int m0 = blockIdx.y * 128, n0 = blockIdx.x * 128;
  f32x4 z = {0.f, 0.f, 0.f, 0.f};
  f32x4 acc[4][4];
#pragma unroll
  for (int i = 0; i < 4; ++i)
#pragma unroll
    for (int j = 0; j < 4; ++j) acc[i][j] = z;

  for (int k0 = 0; k0 < K; k0 += 32) {
#pragma unroll
    for (int it = 0; it < 2; ++it) {
      int c = tid + it * 256;          // 512 chunks of 8 ushorts per tile
      int row = c >> 2, cc = (c & 3) << 3;
      *(bf16x8*)&As[row * AST + cc] = *(const bf16x8*)&A[(size_t)(m0 + row) * lda + k0 + cc];
      *(bf16x8*)&Bs[row * AST + cc] = *(const bf16x8*)&B[(size_t)(n0 + row) * ldb + k0 + cc];
    }
    __syncthreads();
    int rA = lane & 15, kk = (lane >> 4) << 3;
    bf16x8 af[4], bg[4];
#pragma unroll
    for (int i = 0; i < 4; ++i) {
      af[i] = *(const bf16x8*)&As[(wm * 64 + i * 16 + rA) * AST + kk];
      bg[i] = *(const bf16x8*)&Bs[(wn * 64 + i * 16 + rA) * AST + kk];
    }
#pragma unroll
    for (int i = 0; i < 4; ++i)
#pragma unroll
      for (int j = 0; j < 4; ++j)
        acc[i][j] = __builtin_amdgcn_mfma_f32_16x16x32_bf16(af[i], bg[j], acc[i][j], 0, 0, 0);
    __syncthreads();
  }
  int rg = (lane >> 4) << 2;
#pragma unroll
  for (int i = 0; i < 4; ++i)
#pragma unroll
    for (int j = 0; j < 4; ++j) {
      int n = n0 + wn * 64 + j * 16 + (lane & 15);
      float bv = bias ? bias[n] : 0.f;
#pragma unroll
      for (int r = 0; r < 4; ++r) {
        int m = m0 + wm * 64 + i * 16 + rg + r;
        C[(size_t)m * ldc + n] = acc[i][j][r] + bv;
      }
    }
}

// ---------------- LSTM phase: both directions, 16 WGs each; tagged-dataflow sync ----------------
// hex word = (bf16(h) << 16) | (step+1); boundary rows pre-zeroed (tag 0 == expected at s=0).
__global__ __launch_bounds__(256) void k_lstm(const float* __restrict__ xg_f, const float* __restrict__ xg_b,
                                              const float* __restrict__ whh_f, const float* __restrict__ whh_b,
                                              u32* __restrict__ hex_f, u32* __restrict__ hex_b,
                                              u16* __restrict__ hcat) {
  __shared__ u16 wlds[256 * 264];      // per-thread 256 weights (4 gates x 64 k), padded to 264
  __shared__ float hsh[512];
  __shared__ float partial[32 * 4 * 8];
  __shared__ float gl[128];
  int bid = blockIdx.x;
  int dir = bid >> 4, slice = bid & 15;
  const float* xg  = dir ? xg_b : xg_f;
  const float* whh = dir ? whh_b : whh_f;
  u32* hex = dir ? hex_b : hex_f;
  int u0 = slice * 32;
  int tid = threadIdx.x;
  int j = tid >> 3, p = tid & 7;       // unit j (0..31), k-part p (0..7)

  // stage this WG's Whh slice into LDS as bf16: rows gate*512 + u0 + j, cols p*64..p*64+63
  for (int g = 0; g < 4; ++g) {
    int grow = g * 512 + u0 + j;
    const float* wr = &whh[(size_t)grow * 512 + p * 64];
    u16* wd = &wlds[tid * 264 + g * 64];
    for (int kk = 0; kk < 64; ++kk) wd[kk] = f2b(wr[kk]);
  }
  __syncthreads();

  float creg = 0.f;
  int kbase = p * 64;
  for (int s = 0; s < 512; ++s) {
    int t = dir ? (511 - s) : s;
    int rrow = dir ? (t + 1) : t;
    // wait for (and load) previous h: each word self-validates via step tag
    for (int i = tid; i < 512; i += 256) {
      u32 w;
      do {
        w = __hip_atomic_load(&hex[(size_t)rrow * 512 + i], __ATOMIC_RELAXED, __HIP_MEMORY_SCOPE_AGENT);
      } while ((w & 0xFFFFu) != (u32)s);
      hsh[i] = __uint_as_float(w & 0xFFFF0000u);
    }
    __syncthreads();

    float s0 = 0.f, s1 = 0.f, s2 = 0.f, s3 = 0.f;
    const u16* wp = &wlds[tid * 264];
#pragma unroll
    for (int kk = 0; kk < 64; kk += 8) {
      f32x4 ha = *(const f32x4*)&hsh[kbase + kk];
      f32x4 hb = *(const f32x4*)&hsh[kbase + kk + 4];
      bf16x8 w0 = *(const bf16x8*)(wp + 0 * 64 + kk);
      bf16x8 w1 = *(const bf16x8*)(wp + 1 * 64 + kk);
      bf16x8 w2 = *(const bf16x8*)(wp + 2 * 64 + kk);
      bf16x8 w3 = *(const bf16x8*)(wp + 3 * 64 + kk);
      s0 += ha.x*b2fs(w0[0]) + ha.y*b2fs(w0[1]) + ha.z*b2fs(w0[2]) + ha.w*b2fs(w0[3])
          + hb.x*b2fs(w0[4]) + hb.y*b2fs(w0[5]) + hb.z*b2fs(w0[6]) + hb.w*b2fs(w0[7]);
      s1 += ha.x*b2fs(w1[0]) + ha.y*b2fs(w1[1]) + ha.z*b2fs(w1[2]) + ha.w*b2fs(w1[3])
          + hb.x*b2fs(w1[4]) + hb.y*b2fs(w1[5]) + hb.z*b2fs(w1[6]) + hb.w*b2fs(w1[7]);
      s2 += ha.x*b2fs(w2[0]) + ha.y*b2fs(w2[1]) + ha.z*b2fs(w2[2]) + ha.w*b2fs(w2[3])
          + hb.x*b2fs(w2[4]) + hb.y*b2fs(w2[5]) + hb.z*b2fs(w2[6]) + hb.w*b2fs(w2[7]);
      s3 += ha.x*b2fs(w3[0]) + ha.y*b2fs(w3[1]) + ha.z*b2fs(w3[2]) + ha.w*b2fs(w3[3])
          + hb.x*b2fs(w3[4]) + hb.y*b2fs(w3[5]) + hb.z*b2fs(w3[6]) + hb.w*b2fs(w3[7]);
    }
    partial[(j * 4 + 0) * 8 + p] = s0;
    partial[(j * 4 + 1) * 8 + p] = s1;
    partial[(j * 4 + 2) * 8 + p] = s2;
    partial[(j * 4 + 3) * 8 + p] = s3;
    __syncthreads();
    if (tid < 128) {
      int j2 = tid >> 2, g2 = tid & 3;
      float a = xg[(size_t)t * 2048 + g2 * 512 + u0 + j2];
      const float* pp = &partial[(j2 * 4 + g2) * 8];
#pragma unroll
      for (int q = 0; q < 8; ++q) a += pp[q];
      gl[g2 * 32 + j2] = a;
    }
    __syncthreads();
    if (tid < 32) {
      float gi = gl[0 * 32 + tid], gf = gl[1 * 32 + tid], gg = gl[2 * 32 + tid], go = gl[3 * 32 + tid];
      float iv = 1.f / (1.f + __expf(-gi));
      float fv = 1.f / (1.f + __expf(-gf));
      float gv = tanhf(gg);
      float ov = 1.f / (1.f + __expf(-go));
      creg = fv * creg + iv * gv;
      float h = ov * tanhf(creg);
      u16 hb16 = f2b(h);
      int wrow = dir ? t : (t + 1);
      u32 word = ((u32)hb16 << 16) | (u32)(s + 1);
      __hip_atomic_store(&hex[(size_t)wrow * 512 + u0 + tid], word, __ATOMIC_RELAXED, __HIP_MEMORY_SCOPE_AGENT);
      hcat[(size_t)t * 1024 + dir * 512 + u0 + tid] = hb16;
    }
    __syncthreads();
  }
}

// ---------------- span loss: gather proj rows, relu, head matvec, log-softmax NLL ----------------
// 4 samples per block (amortize W2 reads). hid accum over KSP spans x (fwd,back) table rows.
template <int KSP, int C>
__global__ __launch_bounds__(256) void k_span_loss(const float* __restrict__ Pf, const float* __restrict__ Pb,
                                                   const int* __restrict__ lefts, const int* __restrict__ rights,
                                                   const int* __restrict__ tgts, const float* __restrict__ b1,
                                                   const float* __restrict__ W2, const float* __restrict__ b2,
                                                   float* __restrict__ loss_acc) {
  constexpr int NP = KSP * 1024;
  __shared__ float hid[4][1024];
  __shared__ float sc[4][64];
  int tid = threadIdx.x;
  int n0 = blockIdx.x * 4;
  int d = tid * 4;
  f32x4 bv = *(const f32x4*)&b1[d];
#pragma unroll
  for (int ss = 0; ss < 4; ++ss) {
    int n = n0 + ss;
    f32x4 acc = bv;
#pragma unroll
    for (int k = 0; k < KSP; ++k) {
      int l = lefts[n * KSP + k], r = rights[n * KSP + k];
      f32x4 a1 = *(const f32x4*)&Pf[(size_t)r * NP + k * 1024 + d];
      f32x4 a2 = *(const f32x4*)&Pf[(size_t)(l - 1) * NP + k * 1024 + d];
      f32x4 a3 = *(const f32x4*)&Pb[(size_t)l * NP + k * 1024 + d];
      f32x4 a4 = *(const f32x4*)&Pb[(size_t)(r + 1) * NP + k * 1024 + d];
      acc += a1 - a2 + a3 - a4;
    }
    acc.x = fmaxf(acc.x, 0.f); acc.y = fmaxf(acc.y, 0.f);
    acc.z = fmaxf(acc.z, 0.f); acc.w = fmaxf(acc.w, 0.f);
    *(f32x4*)&hid[ss][d] = acc;
  }
  __syncthreads();
  int wave = tid >> 6, lane = tid & 63;
  for (int c = wave; c < C; c += 4) {
    float p0 = 0.f, p1 = 0.f, p2 = 0.f, p3 = 0.f;
    for (int i = lane; i < 1024; i += 64) {
      float w = W2[(size_t)c * 1024 + i];
      p0 += hid[0][i] * w; p1 += hid[1][i] * w; p2 += hid[2][i] * w; p3 += hid[3][i] * w;
    }
#pragma unroll
    for (int o = 32; o; o >>= 1) {
      p0 += __shfl_xor(p0, o); p1 += __shfl_xor(p1, o);
      p2 += __shfl_xor(p2, o); p3 += __shfl_xor(p3, o);
    }
    if (lane == 0) {
      sc[0][c] = p0 + b2[c]; sc[1][c] = p1 + b2[c];
      sc[2][c] = p2 + b2[c]; sc[3][c] = p3 + b2[c];
    }
  }
  __syncthreads();
  {
    int s = wave;  // wave s handles sample n0+s
    float v = (lane < C) ? sc[s][lane] : -1e30f;
    float m = v;
#pragma unroll
    for (int o = 32; o; o >>= 1) m = fmaxf(m, __shfl_xor(m, o));
    float e = (lane < C) ? __expf(v - m) : 0.f;
#pragma unroll
    for (int o = 32; o; o >>= 1) e += __shfl_xor(e, o);
    if (lane == 0) {
      int tg = tgts[n0 + s];
      float loss = m + __logf(e) - sc[s][tg];
      atomicAdd(&loss_acc[(n0 + s) & 255], loss);
    }
  }
}

__global__ __launch_bounds__(256) void k_finalize(const float* __restrict__ acc, float* __restrict__ out) {
  int tid = threadIdx.x;
  __shared__ float s[4];
  float v = acc[tid];
#pragma unroll
  for (int o = 32; o; o >>= 1) v += __shfl_xor(v, o);
  if ((tid & 63) == 0) s[tid >> 6] = v;
  __syncthreads();
  if (tid == 0) out[0] = (s[0] + s[1] + s[2] + s[3]) * (1.0f / 16384.0f);
}

extern "C" void kernel_launch(void* const* d_in, const int* in_sizes, int n_in,
                              void* d_out, int out_size, void* d_ws, size_t ws_size,
                              hipStream_t stream) {
  (void)in_sizes; (void)n_in; (void)out_size; (void)ws_size;
  const int* word_inds = (const int*)d_in[0];
  const int* tag_inds  = (const int*)d_in[1];
  const int* s_tgt = (const int*)d_in[2];
  const int* l_tgt = (const int*)d_in[3];
  const int* s_l = (const int*)d_in[4];
  const int* s_r = (const int*)d_in[5];
  const int* l_l = (const int*)d_in[6];
  const int* l_r = (const int*)d_in[7];
  const float* W_word  = (const float*)d_in[8];
  const float* W_tag   = (const float*)d_in[9];
  const float* Wih_l0f = (const float*)d_in[10];
  const float* Whh_l0f = (const float*)d_in[11];
  const float* b_l0f   = (const float*)d_in[12];
  const float* Wih_l0b = (const float*)d_in[13];
  const float* Whh_l0b = (const float*)d_in[14];
  const float* b_l0b   = (const float*)d_in[15];
  const float* Wih_l1f = (const float*)d_in[16];
  const float* Whh_l1f = (const float*)d_in[17];
  const float* b_l1f   = (const float*)d_in[18];
  const float* Wih_l1b = (const float*)d_in[19];
  const float* Whh_l1b = (const float*)d_in[20];
  const float* b_l1b   = (const float*)d_in[21];
  const float* Ws1 = (const float*)d_in[22];
  const float* bs1 = (const float*)d_in[23];
  const float* Ws2 = (const float*)d_in[24];
  const float* bs2 = (const float*)d_in[25];
  const float* Wl1 = (const float*)d_in[26];
  const float* bl1 = (const float*)d_in[27];
  const float* Wl2 = (const float*)d_in[28];
  const float* bl2 = (const float*)d_in[29];

  char* ws = (char*)d_ws;
  u32* hexf0 = (u32*)(ws + OFF_HEXF0);
  u32* hexb0 = (u32*)(ws + OFF_HEXB0);
  u32* hexf1 = (u32*)(ws + OFF_HEXF1);
  u32* hexb1 = (u32*)(ws + OFF_HEXB1);
  float* lacc = (float*)(ws + OFF_LACC);
  u16* xb    = (u16*)(ws + OFF_XB);
  u16* wih0f = (u16*)(ws + OFF_WIH0F);
  u16* wih0b = (u16*)(ws + OFF_WIH0B);
  u16* wih1f = (u16*)(ws + OFF_WIH1F);
  u16* wih1b = (u16*)(ws + OFF_WIH1B);
  u16* bsall = (u16*)(ws + OFF_BSALL);
  u16* blall = (u16*)(ws + OFF_BLALL);
  u16* hcat0 = (u16*)(ws + OFF_HCAT0);
  u16* hcat1 = (u16*)(ws + OFF_HCAT1);
  float* xg0f = (float*)(ws + OFF_XG0F);
  float* xg0b = (float*)(ws + OFF_XG0B);
  float* xg1f = (float*)(ws + OFF_XG1F);
  float* xg1b = (float*)(ws + OFF_XG1B);
  float* Pfs = (float*)(ws + OFF_PFS);
  float* Pbs = (float*)(ws + OFF_PBS);
  float* Pfl = (float*)(ws + OFF_PFL);
  float* Pbl = (float*)(ws + OFF_PBL);

  // zero the tagged h-exchange buffers (boundary rows + tags) and loss accumulators
  hipMemsetAsync(ws, 0, ZERO_BYTES, stream);

  // prep: embed + weight casts/reorders
  k_embed<<<512, 64, 0, stream>>>(word_inds, tag_inds, W_word, W_tag, xb);
  k_castpad<<<(2048 * 256) / 256, 256, 0, stream>>>(Wih_l0f, wih0f, 250, 256, 2048 * 256);
  k_castpad<<<(2048 * 256) / 256, 256, 0, stream>>>(Wih_l0b, wih0b, 250, 256, 2048 * 256);
  k_castpad<<<(2048 * 1024) / 256, 256, 0, stream>>>(Wih_l1f, wih1f, 1024, 1024, 2048 * 1024);
  k_castpad<<<(2048 * 1024) / 256, 256, 0, stream>>>(Wih_l1b, wih1b, 1024, 1024, 2048 * 1024);
  k_reorder<<<(8 * 1024 * 512) / 256, 256, 0, stream>>>(Ws1, bsall, 4096, 8 * 1024 * 512);
  k_reorder<<<(6 * 1024 * 512) / 256, 256, 0, stream>>>(Wl1, blall, 3072, 6 * 1024 * 512);

  // layer 0 input GEMMs: xg = x @ Wih^T + b
  k_gemm<<<dim3(16, 4), 256, 0, stream>>>(xb, 256, wih0f, 256, xg0f, 2048, b_l0f, 256);
  k_gemm<<<dim3(16, 4), 256, 0, stream>>>(xb, 256, wih0b, 256, xg0b, 2048, b_l0b, 256);
  // layer 0 recurrence (both directions)
  k_lstm<<<32, 256, 0, stream>>>(xg0f, xg0b, Whh_l0f, Whh_l0b, hexf0, hexb0, hcat0);
  // layer 1 input GEMMs
  k_gemm<<<dim3(16, 4), 256, 0, stream>>>(hcat0, 1024, wih1f, 1024, xg1f, 2048, b_l1f, 1024);
  k_gemm<<<dim3(16, 4), 256, 0, stream>>>(hcat0, 1024, wih1b, 1024, xg1b, 2048, b_l1b, 1024);
  // layer 1 recurrence
  k_lstm<<<32, 256, 0, stream>>>(xg1f, xg1b, Whh_l1f, Whh_l1b, hexf1, hexb1, hcat1);

  // per-position projection tables: P[t] = h1[t] @ W1_block^T  (fwd cols 0:512, back cols 512:1024)
  k_gemm<<<dim3(32, 4), 256, 0, stream>>>(hcat1, 1024, bsall, 512, Pfs, 4096, nullptr, 512);
  k_gemm<<<dim3(32, 4), 256, 0, stream>>>(hcat1 + 512, 1024, bsall + (size_t)4096 * 512, 512, Pbs, 4096, nullptr, 512);
  k_gemm<<<dim3(24, 4), 256, 0, stream>>>(hcat1, 1024, blall, 512, Pfl, 3072, nullptr, 512);
  k_gemm<<<dim3(24, 4), 256, 0, stream>>>(hcat1 + 512, 1024, blall + (size_t)3072 * 512, 512, Pbl, 3072, nullptr, 512);

  // span losses + final mean
  k_span_loss<4, 2><<<2048, 256, 0, stream>>>(Pfs, Pbs, s_l, s_r, s_tgt, bs1, Ws2, bs2, lacc);
  k_span_loss<3, 56><<<2048, 256, 0, stream>>>(Pfl, Pbl, l_l, l_r, l_tgt, bl1, Wl2, bl2, lacc);
  k_finalize<<<1, 256, 0, stream>>>(lacc, (float*)d_out);
}

// Round 2
// 2458.766 us; speedup vs baseline: 1.6381x; 1.6381x over previous
//
#include <hip/hip_runtime.h>

using u16 = unsigned short;
using u32 = unsigned int;
typedef __attribute__((ext_vector_type(8))) short bf16x8;
typedef __attribute__((ext_vector_type(4))) float f32x4;

__device__ __forceinline__ u16 f2b(float f) {
  u32 u = __float_as_uint(f);
  return (u16)((u + 0x7fffu + ((u >> 16) & 1u)) >> 16);   // RNE
}
__device__ __forceinline__ float b2fs(short v) { return __uint_as_float(((u32)(u16)v) << 16); }

// ---------------- workspace layout (all offsets 256B-aligned) ----------------
static constexpr size_t HEX_SZ    = (size_t)513 * 512 * 4;           // tagged h-exchange, (T+1)x512 u32
static constexpr size_t OFF_HEXF0 = 0;
static constexpr size_t OFF_HEXB0 = OFF_HEXF0 + HEX_SZ;
static constexpr size_t OFF_HEXF1 = OFF_HEXB0 + HEX_SZ;
static constexpr size_t OFF_HEXB1 = OFF_HEXF1 + HEX_SZ;
static constexpr size_t OFF_LACC  = OFF_HEXB1 + HEX_SZ;              // 256 floats
static constexpr size_t ZERO_BYTES= OFF_LACC + 1024;                 // memset range
static constexpr size_t OFF_XB    = ZERO_BYTES;                      // 512x256 bf16 (embed, padded K)
static constexpr size_t OFF_WIH0F = OFF_XB    + (size_t)512*256*2;
static constexpr size_t OFF_WIH0B = OFF_WIH0F + (size_t)2048*256*2;
static constexpr size_t OFF_WIH1F = OFF_WIH0B + (size_t)2048*256*2;
static constexpr size_t OFF_WIH1B = OFF_WIH1F + (size_t)2048*1024*2;
static constexpr size_t OFF_BSALL = OFF_WIH1B + (size_t)2048*1024*2; // 8192x512 bf16 (Ws1 reordered)
static constexpr size_t OFF_BLALL = OFF_BSALL + (size_t)8192*512*2;  // 6144x512 bf16 (Wl1 reordered)
static constexpr size_t OFF_HCAT0 = OFF_BLALL + (size_t)6144*512*2;  // 512x1024 bf16
static constexpr size_t OFF_HCAT1 = OFF_HCAT0 + (size_t)512*1024*2;
static constexpr size_t OFF_XG0F  = OFF_HCAT1 + (size_t)512*1024*2;  // 512x2048 f32
static constexpr size_t OFF_XG0B  = OFF_XG0F  + (size_t)512*2048*4;
static constexpr size_t OFF_XG1F  = OFF_XG0B  + (size_t)512*2048*4;
static constexpr size_t OFF_XG1B  = OFF_XG1F  + (size_t)512*2048*4;
static constexpr size_t OFF_PFS   = OFF_XG1B  + (size_t)512*2048*4;  // 512x4096 f32
static constexpr size_t OFF_PBS   = OFF_PFS   + (size_t)512*4096*4;
static constexpr size_t OFF_PFL   = OFF_PBS   + (size_t)512*4096*4;  // 512x3072 f32
static constexpr size_t OFF_PBL   = OFF_PFL   + (size_t)512*3072*4;

// ---------------- embedding: x[t] = [W_word[w], W_tag[tg], 0-pad] as bf16 (K padded 250->256) ----
__global__ __launch_bounds__(64) void k_embed(const int* __restrict__ wi, const int* __restrict__ ti,
                                              const float* __restrict__ Ww, const float* __restrict__ Wt,
                                              u16* __restrict__ x) {
  int t = blockIdx.x;
  int w = wi[t], tg = ti[t];
  for (int c = threadIdx.x; c < 256; c += 64) {
    float v = 0.f;
    if (c < 200) v = Ww[(size_t)w * 200 + c];
    else if (c < 250) v = Wt[(size_t)tg * 50 + (c - 200)];
    x[(size_t)t * 256 + c] = f2b(v);
  }
}

// ---------------- fp32 -> bf16 cast with K padding ----------------
__global__ __launch_bounds__(256) void k_castpad(const float* __restrict__ src, u16* __restrict__ dst,
                                                 int K, int Kp, int total) {
  int i = blockIdx.x * 256 + threadIdx.x;
  if (i >= total) return;
  int n = i / Kp, k = i - n * Kp;
  dst[i] = (k < K) ? f2b(src[(size_t)n * K + k]) : (u16)0;
}

// ---- reorder W1 (HID x NC) -> B (NB*1024 x 512) with row n=k*1024+h: B[n][u]=W1[h][k*512+u] ----
__global__ __launch_bounds__(256) void k_reorder(const float* __restrict__ src, u16* __restrict__ dst,
                                                 int NC, int total) {
  int i = blockIdx.x * 256 + threadIdx.x;
  if (i >= total) return;
  int u = i & 511;
  int nidx = i >> 9;
  int k = nidx >> 10, h = nidx & 1023;
  dst[i] = f2b(src[(size_t)h * NC + k * 512 + u]);
}

// ---------------- bf16 MFMA GEMM: C(MxN) = A(MxK) @ B(NxK)^T (+bias) ----------------
// 128x128 tile, BK=32, 256 threads = 4 waves (2x2), wave does 64x64 via 4x4 16x16x32 frags.
#define AST 40  // LDS row stride in ushorts (80B = 5*16B, conflict-free b128 reads)
__global__ __launch_bounds__(256) void k_gemm(const u16* __restrict__ A, int lda,
                                              const u16* __restrict__ B, int ldb,
                                              float* __restrict__ C, int ldc,
                                              const float* __restrict__ bias, int K) {
  __shared__ u16 As[128 * AST];
  __shared__ u16 Bs[128 * AST];
  int tid = threadIdx.x;
  int lane = tid & 63, wave = tid >> 6;
  int wm = wave >> 1, wn = wave & 1;
  int m0 = blockIdx.y * 128, n0 = blockIdx.x * 128;
  f32x4 z = {0.f, 0.f, 0.f, 0.f};
  f32x4 acc[4][4];
#pragma unroll
  for (int i = 0; i < 4; ++i)
#pragma unroll
    for (int j = 0; j < 4; ++j) acc[i][j] = z;

  for (int k0 = 0; k0 < K; k0 += 32) {
#pragma unroll
    for (int it = 0; it < 2; ++it) {
      int c = tid + it * 256;          // 512 chunks of 8 ushorts per tile
      int row = c >> 2, cc = (c & 3) << 3;
      *(bf16x8*)&As[row * AST + cc] = *(const bf16x8*)&A[(size_t)(m0 + row) * lda + k0 + cc];
      *(bf16x8*)&Bs[row * AST + cc] = *(const bf16x8*)&B[(size_t)(n0 + row) * ldb + k0 + cc];
    }
    __syncthreads();
    int rA = lane & 15, kk = (lane >> 4) << 3;
    bf16x8 af[4], bg[4];
#pragma unroll
    for (int i = 0; i < 4; ++i) {
      af[i] = *(const bf16x8*)&As[(wm * 64 + i * 16 + rA) * AST + kk];
      bg[i] = *(const bf16x8*)&Bs[(wn * 64 + i * 16 + rA) * AST + kk];
    }
#pragma unroll
    for (int i = 0; i < 4; ++i)
#pragma unroll
      for (int j = 0; j < 4; ++j)
        acc[i][j] = __builtin_amdgcn_mfma_f32_16x16x32_bf16(af[i], bg[j], acc[i][j], 0, 0, 0);
    __syncthreads();
  }
  int rg = (lane >> 4) << 2;
#pragma unroll
  for (int i = 0; i < 4; ++i)
#pragma unroll
    for (int j = 0; j < 4; ++j) {
      int n = n0 + wn * 64 + j * 16 + (lane & 15);
      float bv = bias ? bias[n] : 0.f;
#pragma unroll
      for (int r = 0; r < 4; ++r) {
        int m = m0 + wm * 64 + i * 16 + rg + r;
        C[(size_t)m * ldc + n] = acc[i][j][r] + bv;
      }
    }
}

// ---------------- LSTM phase: both directions, 16 WGs each; tagged-dataflow sync ----------------
// MFMA matvec: each WG owns 128 output rows (4 gates x 32 units), K=512.
// B-fragments (Whh) live permanently in VGPRs: wave w holds n-tiles {2w, 2w+1},
// each 16 k-tiles of 16x16x32 -> 32 bf16x8 frags = 128 VGPRs/thread.
// A = h broadcast into all 16 M-rows (read row 0 of D).
// hex word = (bf16(h) << 16) | (step+1); boundary rows pre-zeroed (tag 0 == expected at s=0).
__global__ __launch_bounds__(256, 1) void k_lstm(const float* __restrict__ xg_f, const float* __restrict__ xg_b,
                                                 const float* __restrict__ whh_f, const float* __restrict__ whh_b,
                                                 u32* __restrict__ hex_f, u32* __restrict__ hex_b,
                                                 u16* __restrict__ hcat) {
  __shared__ __align__(16) u16 hshb[512];   // current h as bf16
  __shared__ float gl[128];                 // per-WG gate pre-activations (recurrent part)
  int bid = blockIdx.x;
  int dir = bid >> 4, slice = bid & 15;
  const float* xg  = dir ? xg_b : xg_f;
  const float* whh = dir ? whh_b : whh_f;
  u32* hex = dir ? hex_b : hex_f;
  int u0 = slice * 32;
  int tid = threadIdx.x;
  int wave = tid >> 6, lane = tid & 63;
  int col = lane & 15, kgrp = lane >> 4;    // B-frag: col = lane&15, k-chunk = (lane>>4)*8

  // ---- prologue: load this thread's 32 B-fragments of Whh into registers ----
  bf16x8 bfr[2][16];
#pragma unroll
  for (int ntl = 0; ntl < 2; ++ntl) {
    int n = (2 * wave + ntl) * 16 + col;              // 0..127
    int row = (n >> 5) * 512 + u0 + (n & 31);         // gate*512 + u0 + unit
    const float* wr = whh + (size_t)row * 512;
#pragma unroll
    for (int kt = 0; kt < 16; ++kt) {
      int k0 = kt * 32 + kgrp * 8;
      f32x4 w0 = *(const f32x4*)&wr[k0];
      f32x4 w1 = *(const f32x4*)&wr[k0 + 4];
      bf16x8 v;
      v[0] = (short)f2b(w0.x); v[1] = (short)f2b(w0.y);
      v[2] = (short)f2b(w0.z); v[3] = (short)f2b(w0.w);
      v[4] = (short)f2b(w1.x); v[5] = (short)f2b(w1.y);
      v[6] = (short)f2b(w1.z); v[7] = (short)f2b(w1.w);
      bfr[ntl][kt] = v;
    }
  }

  float creg = 0.f;
  for (int s = 0; s < 512; ++s) {
    int t = dir ? (511 - s) : s;
    int rrow = dir ? (t + 1) : t;

    // prefetch the input-GEMM gate values (independent of h) — hides under the spin
    float xga = 0.f, xgb2 = 0.f, xgc = 0.f, xgd = 0.f;
    if (tid < 32) {
      const float* xr = &xg[(size_t)t * 2048 + u0 + tid];
      xga = xr[0]; xgb2 = xr[512]; xgc = xr[1024]; xgd = xr[1536];
    }

    // wait for (and load) previous h: each word self-validates via step tag
    for (int i = tid; i < 512; i += 256) {
      u32 w;
      do {
        w = __hip_atomic_load(&hex[(size_t)rrow * 512 + i], __ATOMIC_RELAXED, __HIP_MEMORY_SCOPE_AGENT);
      } while ((w & 0xFFFFu) != (u32)s);
      hshb[i] = (u16)(w >> 16);
    }
    __syncthreads();

    // MFMA matvec: D[0][n] = sum_k h[k] * Whh[row(n)][k]
    f32x4 z4 = {0.f, 0.f, 0.f, 0.f};
    f32x4 acc0[4], acc1[4];
#pragma unroll
    for (int q = 0; q < 4; ++q) { acc0[q] = z4; acc1[q] = z4; }
#pragma unroll
    for (int kt = 0; kt < 16; ++kt) {
      bf16x8 a = *(const bf16x8*)&hshb[kt * 32 + kgrp * 8];   // broadcast within 16-lane group
      acc0[kt & 3] = __builtin_amdgcn_mfma_f32_16x16x32_bf16(a, bfr[0][kt], acc0[kt & 3], 0, 0, 0);
      acc1[kt & 3] = __builtin_amdgcn_mfma_f32_16x16x32_bf16(a, bfr[1][kt], acc1[kt & 3], 0, 0, 0);
    }
    if (lane < 16) {
      float v0 = acc0[0].x + acc0[1].x + acc0[2].x + acc0[3].x;
      float v1 = acc1[0].x + acc1[1].x + acc1[2].x + acc1[3].x;
      gl[(2 * wave) * 16 + lane] = v0;
      gl[(2 * wave + 1) * 16 + lane] = v1;
    }
    __syncthreads();

    if (tid < 32) {
      float gi = gl[tid] + xga, gf = gl[32 + tid] + xgb2, gg = gl[64 + tid] + xgc, go = gl[96 + tid] + xgd;
      float iv = 1.f / (1.f + __expf(-gi));
      float fv = 1.f / (1.f + __expf(-gf));
      float gv = tanhf(gg);
      float ov = 1.f / (1.f + __expf(-go));
      creg = fv * creg + iv * gv;
      float h = ov * tanhf(creg);
      u16 hb16 = f2b(h);
      int wrow = dir ? t : (t + 1);
      u32 word = ((u32)hb16 << 16) | (u32)(s + 1);
      __hip_atomic_store(&hex[(size_t)wrow * 512 + u0 + tid], word, __ATOMIC_RELAXED, __HIP_MEMORY_SCOPE_AGENT);
      hcat[(size_t)t * 1024 + dir * 512 + u0 + tid] = hb16;
    }
  }
}

// ---------------- span loss: gather proj rows, relu, head matvec, log-softmax NLL ----------------
// 4 samples per block (amortize W2 reads). hid accum over KSP spans x (fwd,back) table rows.
template <int KSP, int C>
__global__ __launch_bounds__(256) void k_span_loss(const float* __restrict__ Pf, const float* __restrict__ Pb,
                                                   const int* __restrict__ lefts, const int* __restrict__ rights,
                                                   const int* __restrict__ tgts, const float* __restrict__ b1,
                                                   const float* __restrict__ W2, const float* __restrict__ b2,
                                                   float* __restrict__ loss_acc) {
  constexpr int NP = KSP * 1024;
  __shared__ float hid[4][1024];
  __shared__ float sc[4][64];
  int tid = threadIdx.x;
  int n0 = blockIdx.x * 4;
  int d = tid * 4;
  f32x4 bv = *(const f32x4*)&b1[d];
#pragma unroll
  for (int ss = 0; ss < 4; ++ss) {
    int n = n0 + ss;
    f32x4 acc = bv;
#pragma unroll
    for (int k = 0; k < KSP; ++k) {
      int l = lefts[n * KSP + k], r = rights[n * KSP + k];
      f32x4 a1 = *(const f32x4*)&Pf[(size_t)r * NP + k * 1024 + d];
      f32x4 a2 = *(const f32x4*)&Pf[(size_t)(l - 1) * NP + k * 1024 + d];
      f32x4 a3 = *(const f32x4*)&Pb[(size_t)l * NP + k * 1024 + d];
      f32x4 a4 = *(const f32x4*)&Pb[(size_t)(r + 1) * NP + k * 1024 + d];
      acc += a1 - a2 + a3 - a4;
    }
    acc.x = fmaxf(acc.x, 0.f); acc.y = fmaxf(acc.y, 0.f);
    acc.z = fmaxf(acc.z, 0.f); acc.w = fmaxf(acc.w, 0.f);
    *(f32x4*)&hid[ss][d] = acc;
  }
  __syncthreads();
  int wave = tid >> 6, lane = tid & 63;
  for (int c = wave; c < C; c += 4) {
    float p0 = 0.f, p1 = 0.f, p2 = 0.f, p3 = 0.f;
    for (int i = lane; i < 1024; i += 64) {
      float w = W2[(size_t)c * 1024 + i];
      p0 += hid[0][i] * w; p1 += hid[1][i] * w; p2 += hid[2][i] * w; p3 += hid[3][i] * w;
    }
#pragma unroll
    for (int o = 32; o; o >>= 1) {
      p0 += __shfl_xor(p0, o); p1 += __shfl_xor(p1, o);
      p2 += __shfl_xor(p2, o); p3 += __shfl_xor(p3, o);
    }
    if (lane == 0) {
      sc[0][c] = p0 + b2[c]; sc[1][c] = p1 + b2[c];
      sc[2][c] = p2 + b2[c]; sc[3][c] = p3 + b2[c];
    }
  }
  __syncthreads();
  {
    int s = wave;  // wave s handles sample n0+s
    float v = (lane < C) ? sc[s][lane] : -1e30f;
    float m = v;
#pragma unroll
    for (int o = 32; o; o >>= 1) m = fmaxf(m, __shfl_xor(m, o));
    float e = (lane < C) ? __expf(v - m) : 0.f;
#pragma unroll
    for (int o = 32; o; o >>= 1) e += __shfl_xor(e, o);
    if (lane == 0) {
      int tg = tgts[n0 + s];
      float loss = m + __logf(e) - sc[s][tg];
      atomicAdd(&loss_acc[(n0 + s) & 255], loss);
    }
  }
}

__global__ __launch_bounds__(256) void k_finalize(const float* __restrict__ acc, float* __restrict__ out) {
  int tid = threadIdx.x;
  __shared__ float s[4];
  float v = acc[tid];
#pragma unroll
  for (int o = 32; o; o >>= 1) v += __shfl_xor(v, o);
  if ((tid & 63) == 0) s[tid >> 6] = v;
  __syncthreads();
  if (tid == 0) out[0] = (s[0] + s[1] + s[2] + s[3]) * (1.0f / 16384.0f);
}

extern "C" void kernel_launch(void* const* d_in, const int* in_sizes, int n_in,
                              void* d_out, int out_size, void* d_ws, size_t ws_size,
                              hipStream_t stream) {
  (void)in_sizes; (void)n_in; (void)out_size; (void)ws_size;
  const int* word_inds = (const int*)d_in[0];
  const int* tag_inds  = (const int*)d_in[1];
  const int* s_tgt = (const int*)d_in[2];
  const int* l_tgt = (const int*)d_in[3];
  const int* s_l = (const int*)d_in[4];
  const int* s_r = (const int*)d_in[5];
  const int* l_l = (const int*)d_in[6];
  const int* l_r = (const int*)d_in[7];
  const float* W_word  = (const float*)d_in[8];
  const float* W_tag   = (const float*)d_in[9];
  const float* Wih_l0f = (const float*)d_in[10];
  const float* Whh_l0f = (const float*)d_in[11];
  const float* b_l0f   = (const float*)d_in[12];
  const float* Wih_l0b = (const float*)d_in[13];
  const float* Whh_l0b = (const float*)d_in[14];
  const float* b_l0b   = (const float*)d_in[15];
  const float* Wih_l1f = (const float*)d_in[16];
  const float* Whh_l1f = (const float*)d_in[17];
  const float* b_l1f   = (const float*)d_in[18];
  const float* Wih_l1b = (const float*)d_in[19];
  const float* Whh_l1b = (const float*)d_in[20];
  const float* b_l1b   = (const float*)d_in[21];
  const float* Ws1 = (const float*)d_in[22];
  const float* bs1 = (const float*)d_in[23];
  const float* Ws2 = (const float*)d_in[24];
  const float* bs2 = (const float*)d_in[25];
  const float* Wl1 = (const float*)d_in[26];
  const float* bl1 = (const float*)d_in[27];
  const float* Wl2 = (const float*)d_in[28];
  const float* bl2 = (const float*)d_in[29];

  char* ws = (char*)d_ws;
  u32* hexf0 = (u32*)(ws + OFF_HEXF0);
  u32* hexb0 = (u32*)(ws + OFF_HEXB0);
  u32* hexf1 = (u32*)(ws + OFF_HEXF1);
  u32* hexb1 = (u32*)(ws + OFF_HEXB1);
  float* lacc = (float*)(ws + OFF_LACC);
  u16* xb    = (u16*)(ws + OFF_XB);
  u16* wih0f = (u16*)(ws + OFF_WIH0F);
  u16* wih0b = (u16*)(ws + OFF_WIH0B);
  u16* wih1f = (u16*)(ws + OFF_WIH1F);
  u16* wih1b = (u16*)(ws + OFF_WIH1B);
  u16* bsall = (u16*)(ws + OFF_BSALL);
  u16* blall = (u16*)(ws + OFF_BLALL);
  u16* hcat0 = (u16*)(ws + OFF_HCAT0);
  u16* hcat1 = (u16*)(ws + OFF_HCAT1);
  float* xg0f = (float*)(ws + OFF_XG0F);
  float* xg0b = (float*)(ws + OFF_XG0B);
  float* xg1f = (float*)(ws + OFF_XG1F);
  float* xg1b = (float*)(ws + OFF_XG1B);
  float* Pfs = (float*)(ws + OFF_PFS);
  float* Pbs = (float*)(ws + OFF_PBS);
  float* Pfl = (float*)(ws + OFF_PFL);
  float* Pbl = (float*)(ws + OFF_PBL);

  // zero the tagged h-exchange buffers (boundary rows + tags) and loss accumulators
  hipMemsetAsync(ws, 0, ZERO_BYTES, stream);

  // prep: embed + weight casts/reorders
  k_embed<<<512, 64, 0, stream>>>(word_inds, tag_inds, W_word, W_tag, xb);
  k_castpad<<<(2048 * 256) / 256, 256, 0, stream>>>(Wih_l0f, wih0f, 250, 256, 2048 * 256);
  k_castpad<<<(2048 * 256) / 256, 256, 0, stream>>>(Wih_l0b, wih0b, 250, 256, 2048 * 256);
  k_castpad<<<(2048 * 1024) / 256, 256, 0, stream>>>(Wih_l1f, wih1f, 1024, 1024, 2048 * 1024);
  k_castpad<<<(2048 * 1024) / 256, 256, 0, stream>>>(Wih_l1b, wih1b, 1024, 1024, 2048 * 1024);
  k_reorder<<<(8 * 1024 * 512) / 256, 256, 0, stream>>>(Ws1, bsall, 4096, 8 * 1024 * 512);
  k_reorder<<<(6 * 1024 * 512) / 256, 256, 0, stream>>>(Wl1, blall, 3072, 6 * 1024 * 512);

  // layer 0 input GEMMs: xg = x @ Wih^T + b
  k_gemm<<<dim3(16, 4), 256, 0, stream>>>(xb, 256, wih0f, 256, xg0f, 2048, b_l0f, 256);
  k_gemm<<<dim3(16, 4), 256, 0, stream>>>(xb, 256, wih0b, 256, xg0b, 2048, b_l0b, 256);
  // layer 0 recurrence (both directions)
  k_lstm<<<32, 256, 0, stream>>>(xg0f, xg0b, Whh_l0f, Whh_l0b, hexf0, hexb0, hcat0);
  // layer 1 input GEMMs
  k_gemm<<<dim3(16, 4), 256, 0, stream>>>(hcat0, 1024, wih1f, 1024, xg1f, 2048, b_l1f, 1024);
  k_gemm<<<dim3(16, 4), 256, 0, stream>>>(hcat0, 1024, wih1b, 1024, xg1b, 2048, b_l1b, 1024);
  // layer 1 recurrence
  k_lstm<<<32, 256, 0, stream>>>(xg1f, xg1b, Whh_l1f, Whh_l1b, hexf1, hexb1, hcat1);

  // per-position projection tables: P[t] = h1[t] @ W1_block^T  (fwd cols 0:512, back cols 512:1024)
  k_gemm<<<dim3(32, 4), 256, 0, stream>>>(hcat1, 1024, bsall, 512, Pfs, 4096, nullptr, 512);
  k_gemm<<<dim3(32, 4), 256, 0, stream>>>(hcat1 + 512, 1024, bsall + (size_t)4096 * 512, 512, Pbs, 4096, nullptr, 512);
  k_gemm<<<dim3(24, 4), 256, 0, stream>>>(hcat1, 1024, blall, 512, Pfl, 3072, nullptr, 512);
  k_gemm<<<dim3(24, 4), 256, 0, stream>>>(hcat1 + 512, 1024, blall + (size_t)3072 * 512, 512, Pbl, 3072, nullptr, 512);

  // span losses + final mean
  k_span_loss<4, 2><<<2048, 256, 0, stream>>>(Pfs, Pbs, s_l, s_r, s_tgt, bs1, Ws2, bs2, lacc);
  k_span_loss<3, 56><<<2048, 256, 0, stream>>>(Pfl, Pbl, l_l, l_r, l_tgt, bl1, Wl2, bl2, lacc);
  k_finalize<<<1, 256, 0, stream>>>(lacc, (float*)d_out);
}